// Round 12
// baseline (545.107 us; speedup 1.0000x reference)
//
#include <hip/hip_runtime.h>
#include <math.h>

#define NPTS 16384
#define BGR 16
#define NPGR 1024
#define KNN 12
#define DM 128
#define DH 256
#define NL 3
#define EDG (NPTS*KNN)

typedef unsigned short u16;
typedef unsigned int u32;
typedef __attribute__((ext_vector_type(8))) short short8;
typedef __attribute__((ext_vector_type(4))) float floatx4;

__device__ __forceinline__ float silu_f(float x) {
    return x / (1.0f + __expf(-x));
}
__device__ __forceinline__ u16 f2bf(float f) {
    union { float f; u32 u; } v; v.f = f;
    u32 r = v.u + 0x7fffu + ((v.u >> 16) & 1u);
    return (u16)(r >> 16);
}
__device__ __forceinline__ float bf2f(u16 b) {
    union { u32 u; float f; } v; v.u = ((u32)b) << 16;
    return v.f;
}
// async global->LDS, 16B per lane; lds dest = wave-uniform base + lane*16
__device__ __forceinline__ void glds16(const u16* gp, u16* lp) {
    __builtin_amdgcn_global_load_lds(
        (const __attribute__((address_space(1))) void*)gp,
        (__attribute__((address_space(3))) void*)lp, 16, 0, 0);
}
// swizzled LDS offset (u16 units): row stride 32 u16 (64B), chunk = quad ^ phase(row)
__device__ __forceinline__ int lofs(int row, int q) {
    return row * 32 + ((q ^ ((row >> 2) & 3)) << 3);
}

// ---------------------------------------------------------------- KNN + edge attrs
// 32 points/block, 8 threads/point, strided conflict-free scan (R8-verified).
#define KPPB 32
__global__ __launch_bounds__(256) void knn_kernel(const float* __restrict__ x,
                                                  int* __restrict__ srcb,
                                                  float* __restrict__ ea) {
#pragma clang fp contract(off)
    __shared__ float2 pxy[NPGR];
    __shared__ float s0[NPGR];
    __shared__ float sdf[256 * 13];
    __shared__ int   sif[256 * 13];
    __shared__ int   sel[KPPB][KNN];
    int t = threadIdx.x;
    int g   = blockIdx.x / (NPGR / KPPB);
    int blk = blockIdx.x % (NPGR / KPPB);
    int base = g * NPGR;
    for (int j = t; j < NPGR; j += 256) {
        const float* xp = x + (size_t)(base + j) * 3;
        s0[j] = xp[0];
        pxy[j] = make_float2(xp[1], xp[2]);
    }
    __syncthreads();
    int r  = t & 7;
    int pt = t >> 3;
    int il = blk * KPPB + pt;
    float2 pil = pxy[il];
    float xi = pil.x, yi = pil.y;
    float nd[KNN]; int ni[KNN];
#pragma unroll
    for (int k = 0; k < KNN; ++k) { nd[k] = 3.4e38f; ni[k] = 0x7fffffff; }
    for (int jj = 0; jj < 128; ++jj) {
        int j = jj * 8 + r;
        if (j == il) continue;
        float2 p = pxy[j];
        float dx = p.x - xi;
        float dy = p.y - yi;
        float dx2 = dx * dx;
        float dy2 = dy * dy;
        float d2 = dx2 + dy2;
        if (d2 < nd[KNN-1]) {
            float cd = d2; int ci = j;
#pragma unroll
            for (int k = 0; k < KNN; ++k) {
                bool sw = cd < nd[k];
                float tdv = sw ? nd[k] : cd;
                nd[k] = sw ? cd : nd[k];
                cd = tdv;
                int tiv = sw ? ni[k] : ci;
                ni[k] = sw ? ci : ni[k];
                ci = tiv;
            }
        }
    }
    int li = pt * 8 + r;
#pragma unroll
    for (int k = 0; k < KNN; ++k) {
        sdf[li * 13 + k] = nd[k];
        sif[li * 13 + k] = ni[k];
    }
    __syncthreads();
    if (r == 0) {
        int head[8];
#pragma unroll
        for (int q = 0; q < 8; ++q) head[q] = 0;
#pragma unroll
        for (int k = 0; k < KNN; ++k) {
            float bd = 3.4e38f; int bi = 0x7fffffff; int bq = 0;
#pragma unroll
            for (int q = 0; q < 8; ++q) {
                int hq = head[q];
                float d = (hq < KNN) ? sdf[(pt * 8 + q) * 13 + hq] : 3.4e38f;
                int  ix = (hq < KNN) ? sif[(pt * 8 + q) * 13 + hq] : 0x7fffffff;
                if (d < bd || (d == bd && ix < bi)) { bd = d; bi = ix; bq = q; }
            }
            head[bq]++;
            sel[pt][k] = bi;
        }
    }
    __syncthreads();
    float x0i = s0[il];
    for (int k = r; k < KNN; k += 8) {
        int j = sel[pt][k];
        size_t e = (size_t)(base + il) * KNN + k;
        srcb[e] = base + j;
        float2 pj = pxy[j];
        float dpx = pj.x - xi, dpy = pj.y - yi;
        float a = dpx * dpx;
        float b = dpy * dpy;
        float dist = sqrtf(a + b + 1e-12f);
        float dsv = s0[j] - x0i;
        *(float4*)(ea + e * 4) = make_float4(dpx, dpy, dist, dsv);
    }
}

// ---------------------------------------------------------------- input MLP, 8 nodes/block, dual-write h
__global__ __launch_bounds__(128) void in_mlp_kernel(const float* __restrict__ x,
    const float* __restrict__ W1, const float* __restrict__ b1,
    const float* __restrict__ W2, const float* __restrict__ b2,
    float* __restrict__ h, u16* __restrict__ hh, u16* __restrict__ hl) {
    __shared__ float hid[8][DM];
    __shared__ float xl[8][3];
    int t = threadIdx.x;
    int nb = blockIdx.x * 8;
    if (t < 24) xl[t / 3][t % 3] = x[(size_t)nb * 3 + t];
    __syncthreads();
    float w0 = W1[t], w1 = W1[DM + t], w2 = W1[2 * DM + t], bb = b1[t];
#pragma unroll
    for (int gi = 0; gi < 8; ++gi) {
        float v = xl[gi][0] * w0 + xl[gi][1] * w1 + xl[gi][2] * w2 + bb;
        hid[gi][t] = silu_f(v);
    }
    __syncthreads();
    float acc[8];
    float b2v = b2[t];
#pragma unroll
    for (int gi = 0; gi < 8; ++gi) acc[gi] = b2v;
    for (int k = 0; k < DM; ++k) {
        float w = W2[k * DM + t];
#pragma unroll
        for (int gi = 0; gi < 8; ++gi) acc[gi] += hid[gi][k] * w;
    }
#pragma unroll
    for (int gi = 0; gi < 8; ++gi) {
        size_t idx = (size_t)(nb + gi) * DM + t;
        float v = acc[gi];
        h[idx] = v;
        u16 hi = f2bf(v);
        hh[idx] = hi;
        hl[idx] = f2bf(v - bf2f(hi));
    }
}

// ---------------------------------------------------------------- split-bf16 MFMA GEMM, 64x128 tile
// 4 waves (2x2), wave tile 32x64. global_load_lds staging + XOR-swizzled LDS.
#define MBM 64
#define MBN 128
#define MBK 32

__global__ __launch_bounds__(256) void mgemm_kernel(
    const u16* __restrict__ A0h, const u16* __restrict__ A0l, int k0, int lda0,
    const u16* __restrict__ A1h, const u16* __restrict__ A1l, int lda1,
    const u16* __restrict__ Wh, const u16* __restrict__ Wl, int K,
    const float* __restrict__ bias, int biasN,
    const float* __restrict__ resid, int ldres,
    float* __restrict__ outf, u16* __restrict__ outh, u16* __restrict__ outl, int ldout,
    int act)
{
    __shared__ __align__(16) u16 Ash[MBM * 32];
    __shared__ __align__(16) u16 Asl[MBM * 32];
    __shared__ __align__(16) u16 Bsh[MBN * 32];
    __shared__ __align__(16) u16 Bsl[MBN * 32];
    int t = threadIdx.x;
    int row0 = blockIdx.x * MBM, col0 = blockIdx.y * MBN;
    int lane = t & 63, w = t >> 6;
    int wm = (w >> 1) * 32, wn = (w & 1) * 64;
    int quad = lane >> 4, r15 = lane & 15;
    int rowl = lane >> 2, slot = lane & 3;

    floatx4 acc[2][4];
#pragma unroll
    for (int m = 0; m < 2; ++m)
#pragma unroll
        for (int n = 0; n < 4; ++n) acc[m][n] = (floatx4){0.f, 0.f, 0.f, 0.f};

    for (int kt = 0; kt < K; kt += MBK) {
        const u16 *Abh, *Abl; int lda, ko;
        if (kt < k0) { Abh = A0h; Abl = A0l; lda = lda0; ko = kt; }
        else         { Abh = A1h; Abl = A1l; lda = lda1; ko = kt - k0; }
        __syncthreads();
        {
            int ra = w * 16 + rowl;
            int gca = (slot ^ ((ra >> 2) & 3)) << 3;
            size_t aoff = (size_t)(row0 + ra) * lda + ko + gca;
            glds16(Abh + aoff, Ash + w * 16 * 32);
            glds16(Abl + aoff, Asl + w * 16 * 32);
            int rb0 = w * 32 + rowl;
            int gc0 = (slot ^ ((rb0 >> 2) & 3)) << 3;
            size_t boff0 = (size_t)(col0 + rb0) * K + kt + gc0;
            glds16(Wh + boff0, Bsh + w * 32 * 32);
            glds16(Wl + boff0, Bsl + w * 32 * 32);
            int rb1 = rb0 + 16;
            int gc1 = (slot ^ ((rb1 >> 2) & 3)) << 3;
            size_t boff1 = (size_t)(col0 + rb1) * K + kt + gc1;
            glds16(Wh + boff1, Bsh + (w * 32 + 16) * 32);
            glds16(Wl + boff1, Bsl + (w * 32 + 16) * 32);
        }
        __syncthreads();
        short8 ah[2], alo[2], bhf[4], blf[4];
#pragma unroll
        for (int m = 0; m < 2; ++m) {
            int off = lofs(wm + m * 16 + r15, quad);
            ah[m]  = *(const short8*)(Ash + off);
            alo[m] = *(const short8*)(Asl + off);
        }
#pragma unroll
        for (int n = 0; n < 4; ++n) {
            int off = lofs(wn + n * 16 + r15, quad);
            bhf[n] = *(const short8*)(Bsh + off);
            blf[n] = *(const short8*)(Bsl + off);
        }
#pragma unroll
        for (int m = 0; m < 2; ++m)
#pragma unroll
            for (int n = 0; n < 4; ++n) {
                acc[m][n] = __builtin_amdgcn_mfma_f32_16x16x32_bf16(ah[m],  bhf[n], acc[m][n], 0, 0, 0);
                acc[m][n] = __builtin_amdgcn_mfma_f32_16x16x32_bf16(ah[m],  blf[n], acc[m][n], 0, 0, 0);
                acc[m][n] = __builtin_amdgcn_mfma_f32_16x16x32_bf16(alo[m], bhf[n], acc[m][n], 0, 0, 0);
            }
    }
#pragma unroll
    for (int n = 0; n < 4; ++n) {
        int col = col0 + wn + n*16 + r15;
        float bv = (bias && col < biasN) ? bias[col] : 0.f;
#pragma unroll
        for (int m = 0; m < 2; ++m) {
#pragma unroll
            for (int reg = 0; reg < 4; ++reg) {
                int row = row0 + wm + m*16 + quad*4 + reg;
                float v = acc[m][n][reg] + bv;
                if (act == 1) v = silu_f(v);
                else if (act == 2) v = tanhf(v);
                if (resid) v += resid[(size_t)row * ldres + col];
                size_t oidx = (size_t)row * ldout + col;
                if (outf) outf[oidx] = v;
                if (outh) {
                    u16 hi = f2bf(v);
                    outh[oidx] = hi;
                    outl[oidx] = f2bf(v - bf2f(hi));
                }
            }
        }
    }
}

// ---------------------------------------------------------------- split-bf16 MFMA GEMM, 128x128 tile
// 4 waves (2x2), wave tile 64x64. global_load_lds + XOR swizzle.
#define M2BM 128
__global__ __launch_bounds__(256) void mgemm128_kernel(
    const u16* __restrict__ A0h, const u16* __restrict__ A0l, int k0, int lda0,
    const u16* __restrict__ A1h, const u16* __restrict__ A1l, int lda1,
    const u16* __restrict__ Wh, const u16* __restrict__ Wl, int K,
    const float* __restrict__ bias, int biasN,
    float* __restrict__ outf, u16* __restrict__ outh, u16* __restrict__ outl, int ldout,
    int act)
{
    __shared__ __align__(16) u16 Ash[M2BM * 32];
    __shared__ __align__(16) u16 Asl[M2BM * 32];
    __shared__ __align__(16) u16 Bsh[MBN * 32];
    __shared__ __align__(16) u16 Bsl[MBN * 32];
    int t = threadIdx.x;
    int row0 = blockIdx.x * M2BM, col0 = blockIdx.y * MBN;
    int lane = t & 63, w = t >> 6;
    int wm = (w >> 1) * 64, wn = (w & 1) * 64;
    int quad = lane >> 4, r15 = lane & 15;
    int rowl = lane >> 2, slot = lane & 3;

    floatx4 acc[4][4];
#pragma unroll
    for (int m = 0; m < 4; ++m)
#pragma unroll
        for (int n = 0; n < 4; ++n) acc[m][n] = (floatx4){0.f, 0.f, 0.f, 0.f};

    for (int kt = 0; kt < K; kt += MBK) {
        const u16 *Abh, *Abl; int lda, ko;
        if (kt < k0) { Abh = A0h; Abl = A0l; lda = lda0; ko = kt; }
        else         { Abh = A1h; Abl = A1l; lda = lda1; ko = kt - k0; }
        __syncthreads();
        {
            int ra0 = w * 32 + rowl;
            int gca0 = (slot ^ ((ra0 >> 2) & 3)) << 3;
            size_t aoff0 = (size_t)(row0 + ra0) * lda + ko + gca0;
            glds16(Abh + aoff0, Ash + w * 32 * 32);
            glds16(Abl + aoff0, Asl + w * 32 * 32);
            int ra1 = ra0 + 16;
            int gca1 = (slot ^ ((ra1 >> 2) & 3)) << 3;
            size_t aoff1 = (size_t)(row0 + ra1) * lda + ko + gca1;
            glds16(Abh + aoff1, Ash + (w * 32 + 16) * 32);
            glds16(Abl + aoff1, Asl + (w * 32 + 16) * 32);
            int rb0 = w * 32 + rowl;
            int gcb0 = (slot ^ ((rb0 >> 2) & 3)) << 3;
            size_t boff0 = (size_t)(col0 + rb0) * K + kt + gcb0;
            glds16(Wh + boff0, Bsh + w * 32 * 32);
            glds16(Wl + boff0, Bsl + w * 32 * 32);
            int rb1 = rb0 + 16;
            int gcb1 = (slot ^ ((rb1 >> 2) & 3)) << 3;
            size_t boff1 = (size_t)(col0 + rb1) * K + kt + gcb1;
            glds16(Wh + boff1, Bsh + (w * 32 + 16) * 32);
            glds16(Wl + boff1, Bsl + (w * 32 + 16) * 32);
        }
        __syncthreads();
        short8 ah[4], alo[4], bhf[4], blf[4];
#pragma unroll
        for (int m = 0; m < 4; ++m) {
            int off = lofs(wm + m * 16 + r15, quad);
            ah[m]  = *(const short8*)(Ash + off);
            alo[m] = *(const short8*)(Asl + off);
        }
#pragma unroll
        for (int n = 0; n < 4; ++n) {
            int off = lofs(wn + n * 16 + r15, quad);
            bhf[n] = *(const short8*)(Bsh + off);
            blf[n] = *(const short8*)(Bsl + off);
        }
#pragma unroll
        for (int m = 0; m < 4; ++m)
#pragma unroll
            for (int n = 0; n < 4; ++n) {
                acc[m][n] = __builtin_amdgcn_mfma_f32_16x16x32_bf16(ah[m],  bhf[n], acc[m][n], 0, 0, 0);
                acc[m][n] = __builtin_amdgcn_mfma_f32_16x16x32_bf16(ah[m],  blf[n], acc[m][n], 0, 0, 0);
                acc[m][n] = __builtin_amdgcn_mfma_f32_16x16x32_bf16(alo[m], bhf[n], acc[m][n], 0, 0, 0);
            }
    }
#pragma unroll
    for (int n = 0; n < 4; ++n) {
        int col = col0 + wn + n*16 + r15;
        float bv = (bias && col < biasN) ? bias[col] : 0.f;
#pragma unroll
        for (int m = 0; m < 4; ++m) {
#pragma unroll
            for (int reg = 0; reg < 4; ++reg) {
                int row = row0 + wm + m*16 + quad*4 + reg;
                float v = acc[m][n][reg] + bv;
                if (act == 1) v = silu_f(v);
                size_t oidx = (size_t)row * ldout + col;
                if (outf) outf[oidx] = v;
                if (outh) {
                    u16 hi = f2bf(v);
                    outh[oidx] = hi;
                    outl[oidx] = f2bf(v - bf2f(hi));
                }
            }
        }
    }
}

// ---------------------------------------------------------------- edge aggregation, 4 nodes/block (R9-verified)
#define EPB 4
__global__ __launch_bounds__(256) void edge_agg_kernel(
    const float* __restrict__ CS,
    const int* __restrict__ srcb, const float* __restrict__ ea,
    const float* __restrict__ W1ea,
    u16* __restrict__ HSh, u16* __restrict__ HSl)
{
    int i0 = blockIdx.x * EPB, t = threadIdx.x;
    __shared__ int ss[EPB][KNN];
    __shared__ float sea[EPB][KNN * 4];
    if (t < EPB * KNN) ss[t / KNN][t % KNN] = srcb[(size_t)i0 * KNN + t];
    if (t < EPB * KNN * 4) sea[t / (KNN * 4)][t % (KNN * 4)] = ea[(size_t)i0 * KNN * 4 + t];
    __syncthreads();
    float wa = W1ea[t], wb = W1ea[DH + t], wc = W1ea[2 * DH + t], wd = W1ea[3 * DH + t];
#pragma unroll
    for (int v4 = 0; v4 < EPB; ++v4) {
        int i = i0 + v4;
        float base = CS[(size_t)i * 512 + t];
        float hs = 0.f;
#pragma unroll
        for (int e = 0; e < KNN; ++e) {
            float v = base + CS[(size_t)ss[v4][e] * 512 + 256 + t]
                    + sea[v4][e * 4 + 0] * wa + sea[v4][e * 4 + 1] * wb
                    + sea[v4][e * 4 + 2] * wc + sea[v4][e * 4 + 3] * wd;
            hs += silu_f(v);
        }
        size_t oidx = (size_t)i * DH + t;
        u16 hi = f2bf(hs);
        HSh[oidx] = hi;
        HSl[oidx] = f2bf(hs - bf2f(hi));
    }
}

// ---------------------------------------------------------------- two-phase graph norm (R8-verified)
__global__ __launch_bounds__(256) void norm_part_kernel(const float* __restrict__ hn,
                                                        float* __restrict__ psum)
{
    int g = blockIdx.x, blk = blockIdx.y;
    int t = threadIdx.x, d = t & 127, half = t >> 7;
    size_t base = ((size_t)g * NPGR + (size_t)blk * 128 + half * 64) * DM;
    float s = 0.f, s2 = 0.f;
    for (int n = 0; n < 64; ++n) {
        float v = hn[base + (size_t)n * DM + d];
        s += v; s2 += v * v;
    }
    __shared__ float ps[2][DM], ps2[2][DM];
    ps[half][d] = s; ps2[half][d] = s2;
    __syncthreads();
    if (t < DM) {
        psum[(((size_t)g * 8 + blk) * 2 + 0) * DM + d] = ps[0][d] + ps[1][d];
        psum[(((size_t)g * 8 + blk) * 2 + 1) * DM + d] = ps2[0][d] + ps2[1][d];
    }
}

__global__ __launch_bounds__(256) void norm_apply_kernel(const float* __restrict__ hn,
    float* __restrict__ h, u16* __restrict__ hh, u16* __restrict__ hl,
    const float* __restrict__ psum,
    const float* __restrict__ w, const float* __restrict__ b, const float* __restrict__ ms)
{
    int g = blockIdx.x, blk = blockIdx.y, t = threadIdx.x;
    __shared__ float mmv[DM], rst[DM], wv[DM], bv[DM];
    if (t < DM) {
        float sum = 0.f, sq = 0.f;
        for (int q = 0; q < 8; ++q) {
            sum += psum[(((size_t)g * 8 + q) * 2 + 0) * DM + t];
            sq  += psum[(((size_t)g * 8 + q) * 2 + 1) * DM + t];
        }
        float mean = sum * (1.0f / NPGR);
        float mm = mean * ms[t];
        float var = sq * (1.0f / NPGR) - 2.f * mm * mean + mm * mm;
        mmv[t] = mm;
        rst[t] = 1.0f / sqrtf(var + 1e-5f);
        wv[t] = w[t]; bv[t] = b[t];
    }
    __syncthreads();
    size_t base = ((size_t)g * NPGR + (size_t)blk * 128) * DM;
    for (int i = t; i < 128 * DM; i += 256) {
        int dd = i & 127;
        float v = hn[base + i];
        float o = wv[dd] * (v - mmv[dd]) * rst[dd] + bv[dd];
        h[base + i] = o;
        u16 hi = f2bf(o);
        hh[base + i] = hi;
        hl[base + i] = f2bf(o - bf2f(hi));
    }
}

// ---------------------------------------------------------------- gate dot (1 node/wave)
__global__ __launch_bounds__(256) void gate_dot_kernel(const float* __restrict__ Gh,
    const float* __restrict__ gW2, const float* __restrict__ gb2,
    float* __restrict__ gl)
{
    int t = threadIdx.x, lane = t & 63, w = t >> 6;
    int node = blockIdx.x * 4 + w;
    const float* gp = Gh + (size_t)node * DM;
    float v = gp[lane] * gW2[lane] + gp[lane + 64] * gW2[lane + 64];
    for (int off = 32; off > 0; off >>= 1) v += __shfl_down(v, off, 64);
    if (lane == 0) gl[node] = v + gb2[0];
}

// ---------------------------------------------------------------- pooling (3 phases)
__global__ __launch_bounds__(256) void pool_stats_kernel(const float* __restrict__ gl,
                                                         float* __restrict__ gstat)
{
    int g = blockIdx.x, t = threadIdx.x, lane = t & 63, w = t >> 6;
    __shared__ float red[4];
    const float* gp = gl + (size_t)g * NPGR;
    float mx = -3.4e38f;
    for (int n = t; n < NPGR; n += 256) mx = fmaxf(mx, gp[n]);
    for (int off = 32; off > 0; off >>= 1) mx = fmaxf(mx, __shfl_down(mx, off, 64));
    if (lane == 0) red[w] = mx;
    __syncthreads();
    float gmax = fmaxf(fmaxf(red[0], red[1]), fmaxf(red[2], red[3]));
    __syncthreads();
    float se = 0.f;
    for (int n = t; n < NPGR; n += 256) se += __expf(gp[n] - gmax);
    for (int off = 32; off > 0; off >>= 1) se += __shfl_down(se, off, 64);
    if (lane == 0) red[w] = se;
    __syncthreads();
    if (t == 0) { gstat[g * 2] = gmax; gstat[g * 2 + 1] = red[0] + red[1] + red[2] + red[3]; }
}

__global__ __launch_bounds__(256) void pool_part_kernel(const float* __restrict__ h,
    const float* __restrict__ gl, const float* __restrict__ gstat,
    float* __restrict__ ppool)
{
    int g = blockIdx.x, blk = blockIdx.y;
    int t = threadIdx.x, d = t & 127, half = t >> 7;
    float gmax = gstat[g * 2];
    size_t nbase = (size_t)g * NPGR + (size_t)blk * 128 + half * 64;
    float p = 0.f;
    for (int n = 0; n < 64; ++n)
        p += __expf(gl[nbase + n] - gmax) * h[(nbase + n) * DM + d];
    __shared__ float ps[2][DM];
    ps[half][d] = p;
    __syncthreads();
    if (t < DM) ppool[((size_t)g * 8 + blk) * DM + d] = ps[0][d] + ps[1][d];
}

__global__ __launch_bounds__(128) void pool_head_kernel(const float* __restrict__ ppool,
    const float* __restrict__ gstat,
    const float* __restrict__ hW1, const float* __restrict__ hb1,
    const float* __restrict__ hW2, const float* __restrict__ hb2,
    float* __restrict__ outp)
{
    int g = blockIdx.x, t = threadIdx.x;
    __shared__ float pl[DM];
    __shared__ float red[2];
    float ssum = gstat[g * 2 + 1];
    float p = 0.f;
    for (int q = 0; q < 8; ++q) p += ppool[((size_t)g * 8 + q) * DM + t];
    pl[t] = p / ssum;
    __syncthreads();
    float a = hb1[t];
    for (int k = 0; k < DM; ++k) a += pl[k] * hW1[k * DM + t];
    a = silu_f(a);
    float vv = a * hW2[t];
    int lane = t & 63, w = t >> 6;
    for (int off = 32; off > 0; off >>= 1) vv += __shfl_down(vv, off, 64);
    if (lane == 0) red[w] = vv;
    __syncthreads();
    if (t == 0) outp[g] = red[0] + red[1] + hb2[0];
}

// ---------------------------------------------------------------- per-layer folded constants
__global__ __launch_bounds__(256) void precompute_kernel(
    const float* __restrict__ msgW2, const float* __restrict__ msgb2,
    const float* __restrict__ updW1, const float* __restrict__ updb1,
    float* __restrict__ W2U, float* __restrict__ bias2)
{
    int bid = blockIdx.x; int t = threadIdx.x;
    if (bid < NL * DH) {
        int l = bid / DH, k = bid % DH;
        const float* w2row = msgW2 + (size_t)l * DH * DM + (size_t)k * DM;
        const float* u1 = updW1 + (size_t)l * 2 * DM * DH;
        float acc = 0.f;
        for (int j = 0; j < DM; ++j) acc += w2row[j] * u1[(size_t)(DM + j) * DH + t];
        W2U[(size_t)l * DH * DH + (size_t)k * DH + t] = acc;
    } else {
        int l = bid - NL * DH;
        const float* u1 = updW1 + (size_t)l * 2 * DM * DH;
        const float* b2 = msgb2 + (size_t)l * DM;
        float acc = updb1[(size_t)l * DH + t];
        for (int j = 0; j < DM; ++j) acc += 12.0f * b2[j] * u1[(size_t)(DM + j) * DH + t];
        bias2[(size_t)l * DH + t] = acc;
    }
}

// ---------------------------------------------------------------- weight transpose + bf16 split (coalesced, R9-verified)
struct WJob { const float* src; u16* dh; u16* dl; int K, N, ldd, off; };
struct WJobs { WJob j[16]; };
__global__ __launch_bounds__(256) void wprep_kernel(WJobs jobs) {
    WJob jb = jobs.j[blockIdx.y];
    int tiles_k = (jb.K + 31) / 32, tiles_n = (jb.N + 31) / 32;
    int tile = blockIdx.x;
    if (tile >= tiles_k * tiles_n) return;
    int kt = (tile % tiles_k) * 32, nt = (tile / tiles_k) * 32;
    __shared__ float tl[32][33];
    int i = threadIdx.x >> 5, j = threadIdx.x & 31;
    for (int r = i; r < 32; r += 8) {
        int k = kt + r, n = nt + j;
        if (k < jb.K && n < jb.N) tl[r][j] = jb.src[(size_t)k * jb.N + n];
    }
    __syncthreads();
    for (int r = i; r < 32; r += 8) {
        int n = nt + r, k = kt + j;
        if (n < jb.N && k < jb.K) {
            float v = tl[j][r];
            u16 hi = f2bf(v);
            u16 lo = f2bf(v - bf2f(hi));
            jb.dh[(size_t)n * jb.ldd + jb.off + k] = hi;
            jb.dl[(size_t)n * jb.ldd + jb.off + k] = lo;
        }
    }
}

extern "C" void kernel_launch(void* const* d_in, const int* in_sizes, int n_in,
                              void* d_out, int out_size, void* d_ws, size_t ws_size,
                              hipStream_t stream) {
    const float* x     = (const float*)d_in[0];
    const float* inW1  = (const float*)d_in[2];
    const float* inb1  = (const float*)d_in[3];
    const float* inW2  = (const float*)d_in[4];
    const float* inb2  = (const float*)d_in[5];
    const float* msgW1 = (const float*)d_in[6];
    const float* msgb1 = (const float*)d_in[7];
    const float* msgW2 = (const float*)d_in[8];
    const float* msgb2 = (const float*)d_in[9];
    const float* updW1 = (const float*)d_in[10];
    const float* updb1 = (const float*)d_in[11];
    const float* updW2 = (const float*)d_in[12];
    const float* updb2 = (const float*)d_in[13];
    const float* nw    = (const float*)d_in[14];
    const float* nb    = (const float*)d_in[15];
    const float* nms   = (const float*)d_in[16];
    const float* gW1   = (const float*)d_in[17];
    const float* gb1   = (const float*)d_in[18];
    const float* gW2   = (const float*)d_in[19];
    const float* gb2   = (const float*)d_in[20];
    const float* hW1   = (const float*)d_in[21];
    const float* hb1   = (const float*)d_in[22];
    const float* hW2   = (const float*)d_in[23];
    const float* hb2   = (const float*)d_in[24];
    float* outp = (float*)d_out;

    float* ws    = (float*)d_ws;
    float* h     = ws;                              // N*DM fp32
    float* CSb   = h + (size_t)NPTS * DM;           // N*512 fp32 [C|S]
    float* hnb   = CSb + (size_t)NPTS * 512;        // N*DM fp32 (hn; also gate hidden)
    float* W2U   = hnb + (size_t)NPTS * DM;         // 3*DH*DH
    float* bias2 = W2U + (size_t)NL * DH * DH;      // 3*DH
    float* glb   = bias2 + NL * DH;                 // N
    int*   srcb  = (int*)(glb + NPTS);              // E
    float* eab   = (float*)(srcb + EDG);            // E*4
    float* psum  = eab + (size_t)EDG * 4;           // 16*8*2*128
    float* gstat = psum + 16 * 8 * 2 * DM;          // 32
    float* ppool = gstat + 32;                      // 16*8*128
    u16* hh  = (u16*)(ppool + 16 * 8 * DM);         // N*DM
    u16* hl  = hh + (size_t)NPTS * DM;
    u16* HSh = hl + (size_t)NPTS * DM;              // N*DH
    u16* HSl = HSh + (size_t)NPTS * DH;
    u16* Th  = HSl + (size_t)NPTS * DH;             // N*DH
    u16* Tl  = Th + (size_t)NPTS * DH;
    u16* WCSh = Tl + (size_t)NPTS * DH;              u16* WCSl = WCSh + (size_t)NL * 512 * DM;
    u16* WTh = WCSl + (size_t)NL * 512 * DM;         u16* WTl = WTh + (size_t)NL * DH * 384;
    u16* WUh = WTl + (size_t)NL * DH * 384;          u16* WUl = WUh + (size_t)NL * DM * DH;
    u16* WGh = WUl + (size_t)NL * DM * DH;           u16* WGl = WGh + (size_t)DM * DM;

    hipLaunchKernelGGL(precompute_kernel, dim3(NL * DH + NL), dim3(DH), 0, stream,
                       msgW2, msgb2, updW1, updb1, W2U, bias2);

    WJobs jobs;
    int ji = 0;
    for (int l = 0; l < NL; ++l) {
        jobs.j[ji++] = WJob{ msgW1 + (size_t)l * 260 * DH,            WCSh + (size_t)l * 512 * DM,            WCSl + (size_t)l * 512 * DM,            128, 256, 128, 0 };
        jobs.j[ji++] = WJob{ msgW1 + (size_t)l * 260 * DH + 128 * DH, WCSh + (size_t)l * 512 * DM + 256 * DM, WCSl + (size_t)l * 512 * DM + 256 * DM, 128, 256, 128, 0 };
        jobs.j[ji++] = WJob{ updW1 + (size_t)l * 256 * DH,            WTh + (size_t)l * DH * 384, WTl + (size_t)l * DH * 384, 128, 256, 384, 0 };
        jobs.j[ji++] = WJob{ W2U   + (size_t)l * DH * DH,             WTh + (size_t)l * DH * 384, WTl + (size_t)l * DH * 384, 256, 256, 384, 128 };
        jobs.j[ji++] = WJob{ updW2 + (size_t)l * DH * DM,             WUh + (size_t)l * DM * DH, WUl + (size_t)l * DM * DH, 256, 128, 256, 0 };
    }
    jobs.j[ji++] = WJob{ gW1, WGh, WGl, 128, 128, 128, 0 };
    hipLaunchKernelGGL(wprep_kernel, dim3(64, 16), dim3(256), 0, stream, jobs);

    hipLaunchKernelGGL(knn_kernel, dim3(NPTS / KPPB), dim3(256), 0, stream, x, srcb, eab);
    hipLaunchKernelGGL(in_mlp_kernel, dim3(NPTS / 8), dim3(128), 0, stream,
                       x, inW1, inb1, inW2, inb2, h, hh, hl);

    for (int l = 0; l < NL; ++l) {
        const float* W1l = msgW1 + (size_t)l * 260 * DH;
        // [C|S] = h @ [W1top|W1mid] + [msg_b1|0]   (128x128 tiles, 512 blocks)
        hipLaunchKernelGGL(mgemm128_kernel, dim3(NPTS / M2BM, 512 / MBN), dim3(256), 0, stream,
            hh, hl, DM, DM, (const u16*)nullptr, (const u16*)nullptr, 0,
            WCSh + (size_t)l * 512 * DM, WCSl + (size_t)l * 512 * DM, DM,
            msgb1 + (size_t)l * DH, 256,
            CSb, (u16*)nullptr, (u16*)nullptr, 512, 0);
        // HS[i] = sum_e silu(C[i] + S[src] + ea.W1ea)  -> split bf16
        hipLaunchKernelGGL(edge_agg_kernel, dim3(NPTS / EPB), dim3(DH), 0, stream,
            CSb, srcb, eab, W1l + (size_t)2 * DM * DH, HSh, HSl);
        // T = silu([h|HS] @ WT + bias2) -> split bf16  (64x128 tiles, 512 blocks)
        hipLaunchKernelGGL(mgemm_kernel, dim3(NPTS / MBM, DH / MBN), dim3(256), 0, stream,
            hh, hl, DM, DM, HSh, HSl, DH,
            WTh + (size_t)l * DH * 384, WTl + (size_t)l * DH * 384, 384,
            bias2 + (size_t)l * DH, DH, (const float*)nullptr, 0,
            (float*)nullptr, Th, Tl, DH, 1);
        // hn = h + T @ U2 + upd_b2
        hipLaunchKernelGGL(mgemm_kernel, dim3(NPTS / MBM, DM / MBN), dim3(256), 0, stream,
            Th, Tl, DH, DH, (const u16*)nullptr, (const u16*)nullptr, 0,
            WUh + (size_t)l * DM * DH, WUl + (size_t)l * DM * DH, DH,
            updb2 + (size_t)l * DM, DM, h, DM,
            hnb, (u16*)nullptr, (u16*)nullptr, DM, 0);
        // h = graph_norm(hn), dual-write
        hipLaunchKernelGGL(norm_part_kernel, dim3(BGR, 8), dim3(256), 0, stream, hnb, psum);
        hipLaunchKernelGGL(norm_apply_kernel, dim3(BGR, 8), dim3(256), 0, stream,
            hnb, h, hh, hl, psum, nw + (size_t)l * DM, nb + (size_t)l * DM, nms + (size_t)l * DM);
    }

    // gate hidden = tanh(h @ gW1 + gb1), then dot with gW2
    hipLaunchKernelGGL(mgemm_kernel, dim3(NPTS / MBM, DM / MBN), dim3(256), 0, stream,
        hh, hl, DM, DM, (const u16*)nullptr, (const u16*)nullptr, 0,
        WGh, WGl, DM, gb1, DM, (const float*)nullptr, 0,
        hnb, (u16*)nullptr, (u16*)nullptr, DM, 2);
    hipLaunchKernelGGL(gate_dot_kernel, dim3(NPTS / 4), dim3(256), 0, stream,
        hnb, gW2, gb2, glb);

    hipLaunchKernelGGL(pool_stats_kernel, dim3(BGR), dim3(256), 0, stream, glb, gstat);
    hipLaunchKernelGGL(pool_part_kernel, dim3(BGR, 8), dim3(256), 0, stream, h, glb, gstat, ppool);
    hipLaunchKernelGGL(pool_head_kernel, dim3(BGR), dim3(128), 0, stream,
        ppool, gstat, hW1, hb1, hW2, hb2, outp);
}

// Round 13
// 532.853 us; speedup vs baseline: 1.0230x; 1.0230x over previous
//
#include <hip/hip_runtime.h>
#include <math.h>

#define NPTS 16384
#define BGR 16
#define NPGR 1024
#define KNN 12
#define DM 128
#define DH 256
#define NL 3
#define EDG (NPTS*KNN)

typedef unsigned short u16;
typedef unsigned int u32;
typedef __attribute__((ext_vector_type(8))) short short8;
typedef __attribute__((ext_vector_type(4))) float floatx4;

__device__ __forceinline__ float silu_f(float x) {
    return x / (1.0f + __expf(-x));
}
__device__ __forceinline__ u16 f2bf(float f) {
    union { float f; u32 u; } v; v.f = f;
    u32 r = v.u + 0x7fffu + ((v.u >> 16) & 1u);
    return (u16)(r >> 16);
}
__device__ __forceinline__ float bf2f(u16 b) {
    union { u32 u; float f; } v; v.u = ((u32)b) << 16;
    return v.f;
}
// async global->LDS, 16B per lane; lds dest = wave-uniform base + lane*16
__device__ __forceinline__ void glds16(const u16* gp, u16* lp) {
    __builtin_amdgcn_global_load_lds(
        (const __attribute__((address_space(1))) void*)gp,
        (__attribute__((address_space(3))) void*)lp, 16, 0, 0);
}
// swizzled LDS offset (u16 units): row stride 32 u16 (64B), chunk = quad ^ phase(row)
__device__ __forceinline__ int lofs(int row, int q) {
    return row * 32 + ((q ^ ((row >> 2) & 3)) << 3);
}

// ---------------------------------------------------------------- KNN + edge attrs (R8-verified)
#define KPPB 32
__global__ __launch_bounds__(256) void knn_kernel(const float* __restrict__ x,
                                                  int* __restrict__ srcb,
                                                  float* __restrict__ ea) {
#pragma clang fp contract(off)
    __shared__ float2 pxy[NPGR];
    __shared__ float s0[NPGR];
    __shared__ float sdf[256 * 13];
    __shared__ int   sif[256 * 13];
    __shared__ int   sel[KPPB][KNN];
    int t = threadIdx.x;
    int g   = blockIdx.x / (NPGR / KPPB);
    int blk = blockIdx.x % (NPGR / KPPB);
    int base = g * NPGR;
    for (int j = t; j < NPGR; j += 256) {
        const float* xp = x + (size_t)(base + j) * 3;
        s0[j] = xp[0];
        pxy[j] = make_float2(xp[1], xp[2]);
    }
    __syncthreads();
    int r  = t & 7;
    int pt = t >> 3;
    int il = blk * KPPB + pt;
    float2 pil = pxy[il];
    float xi = pil.x, yi = pil.y;
    float nd[KNN]; int ni[KNN];
#pragma unroll
    for (int k = 0; k < KNN; ++k) { nd[k] = 3.4e38f; ni[k] = 0x7fffffff; }
    for (int jj = 0; jj < 128; ++jj) {
        int j = jj * 8 + r;
        if (j == il) continue;
        float2 p = pxy[j];
        float dx = p.x - xi;
        float dy = p.y - yi;
        float dx2 = dx * dx;
        float dy2 = dy * dy;
        float d2 = dx2 + dy2;
        if (d2 < nd[KNN-1]) {
            float cd = d2; int ci = j;
#pragma unroll
            for (int k = 0; k < KNN; ++k) {
                bool sw = cd < nd[k];
                float tdv = sw ? nd[k] : cd;
                nd[k] = sw ? cd : nd[k];
                cd = tdv;
                int tiv = sw ? ni[k] : ci;
                ni[k] = sw ? ci : ni[k];
                ci = tiv;
            }
        }
    }
    int li = pt * 8 + r;
#pragma unroll
    for (int k = 0; k < KNN; ++k) {
        sdf[li * 13 + k] = nd[k];
        sif[li * 13 + k] = ni[k];
    }
    __syncthreads();
    if (r == 0) {
        int head[8];
#pragma unroll
        for (int q = 0; q < 8; ++q) head[q] = 0;
#pragma unroll
        for (int k = 0; k < KNN; ++k) {
            float bd = 3.4e38f; int bi = 0x7fffffff; int bq = 0;
#pragma unroll
            for (int q = 0; q < 8; ++q) {
                int hq = head[q];
                float d = (hq < KNN) ? sdf[(pt * 8 + q) * 13 + hq] : 3.4e38f;
                int  ix = (hq < KNN) ? sif[(pt * 8 + q) * 13 + hq] : 0x7fffffff;
                if (d < bd || (d == bd && ix < bi)) { bd = d; bi = ix; bq = q; }
            }
            head[bq]++;
            sel[pt][k] = bi;
        }
    }
    __syncthreads();
    float x0i = s0[il];
    for (int k = r; k < KNN; k += 8) {
        int j = sel[pt][k];
        size_t e = (size_t)(base + il) * KNN + k;
        srcb[e] = base + j;
        float2 pj = pxy[j];
        float dpx = pj.x - xi, dpy = pj.y - yi;
        float a = dpx * dpx;
        float b = dpy * dpy;
        float dist = sqrtf(a + b + 1e-12f);
        float dsv = s0[j] - x0i;
        *(float4*)(ea + e * 4) = make_float4(dpx, dpy, dist, dsv);
    }
}

// ---------------------------------------------------------------- input MLP, 8 nodes/block, dual-write h
__global__ __launch_bounds__(128) void in_mlp_kernel(const float* __restrict__ x,
    const float* __restrict__ W1, const float* __restrict__ b1,
    const float* __restrict__ W2, const float* __restrict__ b2,
    float* __restrict__ h, u16* __restrict__ hh, u16* __restrict__ hl) {
    __shared__ float hid[8][DM];
    __shared__ float xl[8][3];
    int t = threadIdx.x;
    int nb = blockIdx.x * 8;
    if (t < 24) xl[t / 3][t % 3] = x[(size_t)nb * 3 + t];
    __syncthreads();
    float w0 = W1[t], w1 = W1[DM + t], w2 = W1[2 * DM + t], bb = b1[t];
#pragma unroll
    for (int gi = 0; gi < 8; ++gi) {
        float v = xl[gi][0] * w0 + xl[gi][1] * w1 + xl[gi][2] * w2 + bb;
        hid[gi][t] = silu_f(v);
    }
    __syncthreads();
    float acc[8];
    float b2v = b2[t];
#pragma unroll
    for (int gi = 0; gi < 8; ++gi) acc[gi] = b2v;
    for (int k = 0; k < DM; ++k) {
        float w = W2[k * DM + t];
#pragma unroll
        for (int gi = 0; gi < 8; ++gi) acc[gi] += hid[gi][k] * w;
    }
#pragma unroll
    for (int gi = 0; gi < 8; ++gi) {
        size_t idx = (size_t)(nb + gi) * DM + t;
        float v = acc[gi];
        h[idx] = v;
        u16 hi = f2bf(v);
        hh[idx] = hi;
        hl[idx] = f2bf(v - bf2f(hi));
    }
}

// ---------------------------------------------------------------- split-bf16 MFMA GEMM, 64x128 tile
#define MBM 64
#define MBN 128
#define MBK 32

__global__ __launch_bounds__(256) void mgemm_kernel(
    const u16* __restrict__ A0h, const u16* __restrict__ A0l, int k0, int lda0,
    const u16* __restrict__ A1h, const u16* __restrict__ A1l, int lda1,
    const u16* __restrict__ Wh, const u16* __restrict__ Wl, int K,
    const float* __restrict__ bias, int biasN,
    const float* __restrict__ resid, int ldres,
    float* __restrict__ outf, u16* __restrict__ outh, u16* __restrict__ outl, int ldout,
    int act)
{
    __shared__ __align__(16) u16 Ash[MBM * 32];
    __shared__ __align__(16) u16 Asl[MBM * 32];
    __shared__ __align__(16) u16 Bsh[MBN * 32];
    __shared__ __align__(16) u16 Bsl[MBN * 32];
    int t = threadIdx.x;
    int row0 = blockIdx.x * MBM, col0 = blockIdx.y * MBN;
    int lane = t & 63, w = t >> 6;
    int wm = (w >> 1) * 32, wn = (w & 1) * 64;
    int quad = lane >> 4, r15 = lane & 15;
    int rowl = lane >> 2, slot = lane & 3;

    floatx4 acc[2][4];
#pragma unroll
    for (int m = 0; m < 2; ++m)
#pragma unroll
        for (int n = 0; n < 4; ++n) acc[m][n] = (floatx4){0.f, 0.f, 0.f, 0.f};

    for (int kt = 0; kt < K; kt += MBK) {
        const u16 *Abh, *Abl; int lda, ko;
        if (kt < k0) { Abh = A0h; Abl = A0l; lda = lda0; ko = kt; }
        else         { Abh = A1h; Abl = A1l; lda = lda1; ko = kt - k0; }
        __syncthreads();
        {
            int ra = w * 16 + rowl;
            int gca = (slot ^ ((ra >> 2) & 3)) << 3;
            size_t aoff = (size_t)(row0 + ra) * lda + ko + gca;
            glds16(Abh + aoff, Ash + w * 16 * 32);
            glds16(Abl + aoff, Asl + w * 16 * 32);
            int rb0 = w * 32 + rowl;
            int gc0 = (slot ^ ((rb0 >> 2) & 3)) << 3;
            size_t boff0 = (size_t)(col0 + rb0) * K + kt + gc0;
            glds16(Wh + boff0, Bsh + w * 32 * 32);
            glds16(Wl + boff0, Bsl + w * 32 * 32);
            int rb1 = rb0 + 16;
            int gc1 = (slot ^ ((rb1 >> 2) & 3)) << 3;
            size_t boff1 = (size_t)(col0 + rb1) * K + kt + gc1;
            glds16(Wh + boff1, Bsh + (w * 32 + 16) * 32);
            glds16(Wl + boff1, Bsl + (w * 32 + 16) * 32);
        }
        __syncthreads();
        short8 ah[2], alo[2], bhf[4], blf[4];
#pragma unroll
        for (int m = 0; m < 2; ++m) {
            int off = lofs(wm + m * 16 + r15, quad);
            ah[m]  = *(const short8*)(Ash + off);
            alo[m] = *(const short8*)(Asl + off);
        }
#pragma unroll
        for (int n = 0; n < 4; ++n) {
            int off = lofs(wn + n * 16 + r15, quad);
            bhf[n] = *(const short8*)(Bsh + off);
            blf[n] = *(const short8*)(Bsl + off);
        }
#pragma unroll
        for (int m = 0; m < 2; ++m)
#pragma unroll
            for (int n = 0; n < 4; ++n) {
                acc[m][n] = __builtin_amdgcn_mfma_f32_16x16x32_bf16(ah[m],  bhf[n], acc[m][n], 0, 0, 0);
                acc[m][n] = __builtin_amdgcn_mfma_f32_16x16x32_bf16(ah[m],  blf[n], acc[m][n], 0, 0, 0);
                acc[m][n] = __builtin_amdgcn_mfma_f32_16x16x32_bf16(alo[m], bhf[n], acc[m][n], 0, 0, 0);
            }
    }
#pragma unroll
    for (int n = 0; n < 4; ++n) {
        int col = col0 + wn + n*16 + r15;
        float bv = (bias && col < biasN) ? bias[col] : 0.f;
#pragma unroll
        for (int m = 0; m < 2; ++m) {
#pragma unroll
            for (int reg = 0; reg < 4; ++reg) {
                int row = row0 + wm + m*16 + quad*4 + reg;
                float v = acc[m][n][reg] + bv;
                if (act == 1) v = silu_f(v);
                else if (act == 2) v = tanhf(v);
                if (resid) v += resid[(size_t)row * ldres + col];
                size_t oidx = (size_t)row * ldout + col;
                if (outf) outf[oidx] = v;
                if (outh) {
                    u16 hi = f2bf(v);
                    outh[oidx] = hi;
                    outl[oidx] = f2bf(v - bf2f(hi));
                }
            }
        }
    }
}

// ---------------------------------------------------------------- split-bf16 MFMA GEMM, 128x128 tile
#define M2BM 128
__global__ __launch_bounds__(256) void mgemm128_kernel(
    const u16* __restrict__ A0h, const u16* __restrict__ A0l, int k0, int lda0,
    const u16* __restrict__ A1h, const u16* __restrict__ A1l, int lda1,
    const u16* __restrict__ Wh, const u16* __restrict__ Wl, int K,
    const float* __restrict__ bias, int biasN,
    float* __restrict__ outf, u16* __restrict__ outh, u16* __restrict__ outl, int ldout,
    int act)
{
    __shared__ __align__(16) u16 Ash[M2BM * 32];
    __shared__ __align__(16) u16 Asl[M2BM * 32];
    __shared__ __align__(16) u16 Bsh[MBN * 32];
    __shared__ __align__(16) u16 Bsl[MBN * 32];
    int t = threadIdx.x;
    int row0 = blockIdx.x * M2BM, col0 = blockIdx.y * MBN;
    int lane = t & 63, w = t >> 6;
    int wm = (w >> 1) * 64, wn = (w & 1) * 64;
    int quad = lane >> 4, r15 = lane & 15;
    int rowl = lane >> 2, slot = lane & 3;

    floatx4 acc[4][4];
#pragma unroll
    for (int m = 0; m < 4; ++m)
#pragma unroll
        for (int n = 0; n < 4; ++n) acc[m][n] = (floatx4){0.f, 0.f, 0.f, 0.f};

    for (int kt = 0; kt < K; kt += MBK) {
        const u16 *Abh, *Abl; int lda, ko;
        if (kt < k0) { Abh = A0h; Abl = A0l; lda = lda0; ko = kt; }
        else         { Abh = A1h; Abl = A1l; lda = lda1; ko = kt - k0; }
        __syncthreads();
        {
            int ra0 = w * 32 + rowl;
            int gca0 = (slot ^ ((ra0 >> 2) & 3)) << 3;
            size_t aoff0 = (size_t)(row0 + ra0) * lda + ko + gca0;
            glds16(Abh + aoff0, Ash + w * 32 * 32);
            glds16(Abl + aoff0, Asl + w * 32 * 32);
            int ra1 = ra0 + 16;
            int gca1 = (slot ^ ((ra1 >> 2) & 3)) << 3;
            size_t aoff1 = (size_t)(row0 + ra1) * lda + ko + gca1;
            glds16(Abh + aoff1, Ash + (w * 32 + 16) * 32);
            glds16(Abl + aoff1, Asl + (w * 32 + 16) * 32);
            int rb0 = w * 32 + rowl;
            int gcb0 = (slot ^ ((rb0 >> 2) & 3)) << 3;
            size_t boff0 = (size_t)(col0 + rb0) * K + kt + gcb0;
            glds16(Wh + boff0, Bsh + w * 32 * 32);
            glds16(Wl + boff0, Bsl + w * 32 * 32);
            int rb1 = rb0 + 16;
            int gcb1 = (slot ^ ((rb1 >> 2) & 3)) << 3;
            size_t boff1 = (size_t)(col0 + rb1) * K + kt + gcb1;
            glds16(Wh + boff1, Bsh + (w * 32 + 16) * 32);
            glds16(Wl + boff1, Bsl + (w * 32 + 16) * 32);
        }
        __syncthreads();
        short8 ah[4], alo[4], bhf[4], blf[4];
#pragma unroll
        for (int m = 0; m < 4; ++m) {
            int off = lofs(wm + m * 16 + r15, quad);
            ah[m]  = *(const short8*)(Ash + off);
            alo[m] = *(const short8*)(Asl + off);
        }
#pragma unroll
        for (int n = 0; n < 4; ++n) {
            int off = lofs(wn + n * 16 + r15, quad);
            bhf[n] = *(const short8*)(Bsh + off);
            blf[n] = *(const short8*)(Bsl + off);
        }
#pragma unroll
        for (int m = 0; m < 4; ++m)
#pragma unroll
            for (int n = 0; n < 4; ++n) {
                acc[m][n] = __builtin_amdgcn_mfma_f32_16x16x32_bf16(ah[m],  bhf[n], acc[m][n], 0, 0, 0);
                acc[m][n] = __builtin_amdgcn_mfma_f32_16x16x32_bf16(ah[m],  blf[n], acc[m][n], 0, 0, 0);
                acc[m][n] = __builtin_amdgcn_mfma_f32_16x16x32_bf16(alo[m], bhf[n], acc[m][n], 0, 0, 0);
            }
    }
#pragma unroll
    for (int n = 0; n < 4; ++n) {
        int col = col0 + wn + n*16 + r15;
        float bv = (bias && col < biasN) ? bias[col] : 0.f;
#pragma unroll
        for (int m = 0; m < 4; ++m) {
#pragma unroll
            for (int reg = 0; reg < 4; ++reg) {
                int row = row0 + wm + m*16 + quad*4 + reg;
                float v = acc[m][n][reg] + bv;
                if (act == 1) v = silu_f(v);
                size_t oidx = (size_t)row * ldout + col;
                if (outf) outf[oidx] = v;
                if (outh) {
                    u16 hi = f2bf(v);
                    outh[oidx] = hi;
                    outl[oidx] = f2bf(v - bf2f(hi));
                }
            }
        }
    }
}

// ---------------------------------------------------------------- gate GEMM with fused tanh-dot
// gl[row] = sum_c tanh( (hh@WG^T)[row][c] + gb1[c] ) * gW2[c] + gb2
__global__ __launch_bounds__(256) void gate_gemm_kernel(
    const u16* __restrict__ Ah, const u16* __restrict__ Al,
    const u16* __restrict__ Wh, const u16* __restrict__ Wl,
    const float* __restrict__ gb1, const float* __restrict__ gW2,
    const float* __restrict__ gb2, float* __restrict__ gl)
{
    __shared__ __align__(16) u16 Ash[64 * 32];
    __shared__ __align__(16) u16 Asl[64 * 32];
    __shared__ __align__(16) u16 Bsh[128 * 32];
    __shared__ __align__(16) u16 Bsl[128 * 32];
    __shared__ float gpart[2][64];
    int t = threadIdx.x;
    int row0 = blockIdx.x * 64;
    int lane = t & 63, w = t >> 6;
    int wm = (w >> 1) * 32, wn = (w & 1) * 64;
    int quad = lane >> 4, r15 = lane & 15;
    int rowl = lane >> 2, slot = lane & 3;

    floatx4 acc[2][4];
#pragma unroll
    for (int m = 0; m < 2; ++m)
#pragma unroll
        for (int n = 0; n < 4; ++n) acc[m][n] = (floatx4){0.f,0.f,0.f,0.f};

    for (int kt = 0; kt < DM; kt += 32) {
        __syncthreads();
        {
            int ra = w * 16 + rowl;
            int gca = (slot ^ ((ra >> 2) & 3)) << 3;
            size_t aoff = (size_t)(row0 + ra) * DM + kt + gca;
            glds16(Ah + aoff, Ash + w * 16 * 32);
            glds16(Al + aoff, Asl + w * 16 * 32);
            int rb0 = w * 32 + rowl;
            int gc0 = (slot ^ ((rb0 >> 2) & 3)) << 3;
            size_t boff0 = (size_t)rb0 * DM + kt + gc0;
            glds16(Wh + boff0, Bsh + w * 32 * 32);
            glds16(Wl + boff0, Bsl + w * 32 * 32);
            int rb1 = rb0 + 16;
            int gc1 = (slot ^ ((rb1 >> 2) & 3)) << 3;
            size_t boff1 = (size_t)rb1 * DM + kt + gc1;
            glds16(Wh + boff1, Bsh + (w * 32 + 16) * 32);
            glds16(Wl + boff1, Bsl + (w * 32 + 16) * 32);
        }
        __syncthreads();
        short8 ah[2], alo[2], bhf[4], blf[4];
#pragma unroll
        for (int m = 0; m < 2; ++m) {
            int off = lofs(wm + m*16 + r15, quad);
            ah[m]  = *(const short8*)(Ash + off);
            alo[m] = *(const short8*)(Asl + off);
        }
#pragma unroll
        for (int n = 0; n < 4; ++n) {
            int off = lofs(wn + n*16 + r15, quad);
            bhf[n] = *(const short8*)(Bsh + off);
            blf[n] = *(const short8*)(Bsl + off);
        }
#pragma unroll
        for (int m = 0; m < 2; ++m)
#pragma unroll
            for (int n = 0; n < 4; ++n) {
                acc[m][n] = __builtin_amdgcn_mfma_f32_16x16x32_bf16(ah[m],  bhf[n], acc[m][n], 0, 0, 0);
                acc[m][n] = __builtin_amdgcn_mfma_f32_16x16x32_bf16(ah[m],  blf[n], acc[m][n], 0, 0, 0);
                acc[m][n] = __builtin_amdgcn_mfma_f32_16x16x32_bf16(alo[m], bhf[n], acc[m][n], 0, 0, 0);
            }
    }
    float rowdot[2][4];
#pragma unroll
    for (int m = 0; m < 2; ++m)
#pragma unroll
        for (int reg = 0; reg < 4; ++reg) rowdot[m][reg] = 0.f;
#pragma unroll
    for (int n = 0; n < 4; ++n) {
        int col = wn + n*16 + r15;
        float bv = gb1[col], wv = gW2[col];
#pragma unroll
        for (int m = 0; m < 2; ++m)
#pragma unroll
            for (int reg = 0; reg < 4; ++reg)
                rowdot[m][reg] += tanhf(acc[m][n][reg] + bv) * wv;
    }
#pragma unroll
    for (int m = 0; m < 2; ++m)
#pragma unroll
        for (int reg = 0; reg < 4; ++reg) {
            float v = rowdot[m][reg];
            v += __shfl_xor(v, 1, 64); v += __shfl_xor(v, 2, 64);
            v += __shfl_xor(v, 4, 64); v += __shfl_xor(v, 8, 64);
            if (r15 == 0) gpart[w & 1][wm + m*16 + quad*4 + reg] = v;
        }
    __syncthreads();
    if (t < 64) gl[row0 + t] = gpart[0][t] + gpart[1][t] + gb2[0];
}

// ---------------------------------------------------------------- edge aggregation, 8 nodes/block
#define EPB 8
__global__ __launch_bounds__(256) void edge_agg_kernel(
    const float* __restrict__ CS,
    const int* __restrict__ srcb, const float* __restrict__ ea,
    const float* __restrict__ W1ea,
    u16* __restrict__ HSh, u16* __restrict__ HSl)
{
    int i0 = blockIdx.x * EPB, t = threadIdx.x;
    __shared__ int ss[EPB][KNN];
    __shared__ float sea[EPB][KNN * 4];
    if (t < EPB * KNN) ss[t / KNN][t % KNN] = srcb[(size_t)i0 * KNN + t];
    for (int idx = t; idx < EPB * KNN * 4; idx += 256)
        sea[idx / (KNN * 4)][idx % (KNN * 4)] = ea[(size_t)i0 * KNN * 4 + idx];
    __syncthreads();
    float wa = W1ea[t], wb = W1ea[DH + t], wc = W1ea[2 * DH + t], wd = W1ea[3 * DH + t];
#pragma unroll
    for (int v4 = 0; v4 < EPB; ++v4) {
        int i = i0 + v4;
        float base = CS[(size_t)i * 512 + t];
        float hs = 0.f;
#pragma unroll
        for (int e = 0; e < KNN; ++e) {
            float v = base + CS[(size_t)ss[v4][e] * 512 + 256 + t]
                    + sea[v4][e * 4 + 0] * wa + sea[v4][e * 4 + 1] * wb
                    + sea[v4][e * 4 + 2] * wc + sea[v4][e * 4 + 3] * wd;
            hs += silu_f(v);
        }
        size_t oidx = (size_t)i * DH + t;
        u16 hi = f2bf(hs);
        HSh[oidx] = hi;
        HSl[oidx] = f2bf(hs - bf2f(hi));
    }
}

// ---------------------------------------------------------------- two-phase graph norm (R8-verified)
__global__ __launch_bounds__(256) void norm_part_kernel(const float* __restrict__ hn,
                                                        float* __restrict__ psum)
{
    int g = blockIdx.x, blk = blockIdx.y;
    int t = threadIdx.x, d = t & 127, half = t >> 7;
    size_t base = ((size_t)g * NPGR + (size_t)blk * 128 + half * 64) * DM;
    float s = 0.f, s2 = 0.f;
    for (int n = 0; n < 64; ++n) {
        float v = hn[base + (size_t)n * DM + d];
        s += v; s2 += v * v;
    }
    __shared__ float ps[2][DM], ps2[2][DM];
    ps[half][d] = s; ps2[half][d] = s2;
    __syncthreads();
    if (t < DM) {
        psum[(((size_t)g * 8 + blk) * 2 + 0) * DM + d] = ps[0][d] + ps[1][d];
        psum[(((size_t)g * 8 + blk) * 2 + 1) * DM + d] = ps2[0][d] + ps2[1][d];
    }
}

__global__ __launch_bounds__(256) void norm_apply_kernel(const float* __restrict__ hn,
    float* __restrict__ h, u16* __restrict__ hh, u16* __restrict__ hl,
    const float* __restrict__ psum,
    const float* __restrict__ w, const float* __restrict__ b, const float* __restrict__ ms)
{
    int g = blockIdx.x, blk = blockIdx.y, t = threadIdx.x;
    __shared__ float mmv[DM], rst[DM], wv[DM], bv[DM];
    if (t < DM) {
        float sum = 0.f, sq = 0.f;
        for (int q = 0; q < 8; ++q) {
            sum += psum[(((size_t)g * 8 + q) * 2 + 0) * DM + t];
            sq  += psum[(((size_t)g * 8 + q) * 2 + 1) * DM + t];
        }
        float mean = sum * (1.0f / NPGR);
        float mm = mean * ms[t];
        float var = sq * (1.0f / NPGR) - 2.f * mm * mean + mm * mm;
        mmv[t] = mm;
        rst[t] = 1.0f / sqrtf(var + 1e-5f);
        wv[t] = w[t]; bv[t] = b[t];
    }
    __syncthreads();
    size_t base = ((size_t)g * NPGR + (size_t)blk * 128) * DM;
    for (int i = t; i < 128 * DM; i += 256) {
        int dd = i & 127;
        float v = hn[base + i];
        float o = wv[dd] * (v - mmv[dd]) * rst[dd] + bv[dd];
        h[base + i] = o;
        u16 hi = f2bf(o);
        hh[base + i] = hi;
        hl[base + i] = f2bf(o - bf2f(hi));
    }
}

// ---------------------------------------------------------------- pooling (3 phases)
__global__ __launch_bounds__(256) void pool_stats_kernel(const float* __restrict__ gl,
                                                         float* __restrict__ gstat)
{
    int g = blockIdx.x, t = threadIdx.x, lane = t & 63, w = t >> 6;
    __shared__ float red[4];
    const float* gp = gl + (size_t)g * NPGR;
    float mx = -3.4e38f;
    for (int n = t; n < NPGR; n += 256) mx = fmaxf(mx, gp[n]);
    for (int off = 32; off > 0; off >>= 1) mx = fmaxf(mx, __shfl_down(mx, off, 64));
    if (lane == 0) red[w] = mx;
    __syncthreads();
    float gmax = fmaxf(fmaxf(red[0], red[1]), fmaxf(red[2], red[3]));
    __syncthreads();
    float se = 0.f;
    for (int n = t; n < NPGR; n += 256) se += __expf(gp[n] - gmax);
    for (int off = 32; off > 0; off >>= 1) se += __shfl_down(se, off, 64);
    if (lane == 0) red[w] = se;
    __syncthreads();
    if (t == 0) { gstat[g * 2] = gmax; gstat[g * 2 + 1] = red[0] + red[1] + red[2] + red[3]; }
}

__global__ __launch_bounds__(256) void pool_part_kernel(const float* __restrict__ h,
    const float* __restrict__ gl, const float* __restrict__ gstat,
    float* __restrict__ ppool)
{
    int g = blockIdx.x, blk = blockIdx.y;
    int t = threadIdx.x, d = t & 127, half = t >> 7;
    float gmax = gstat[g * 2];
    size_t nbase = (size_t)g * NPGR + (size_t)blk * 128 + half * 64;
    float p = 0.f;
    for (int n = 0; n < 64; ++n)
        p += __expf(gl[nbase + n] - gmax) * h[(nbase + n) * DM + d];
    __shared__ float ps[2][DM];
    ps[half][d] = p;
    __syncthreads();
    if (t < DM) ppool[((size_t)g * 8 + blk) * DM + d] = ps[0][d] + ps[1][d];
}

__global__ __launch_bounds__(128) void pool_head_kernel(const float* __restrict__ ppool,
    const float* __restrict__ gstat,
    const float* __restrict__ hW1, const float* __restrict__ hb1,
    const float* __restrict__ hW2, const float* __restrict__ hb2,
    float* __restrict__ outp)
{
    int g = blockIdx.x, t = threadIdx.x;
    __shared__ float pl[DM];
    __shared__ float red[2];
    float ssum = gstat[g * 2 + 1];
    float p = 0.f;
    for (int q = 0; q < 8; ++q) p += ppool[((size_t)g * 8 + q) * DM + t];
    pl[t] = p / ssum;
    __syncthreads();
    float a = hb1[t];
    for (int k = 0; k < DM; ++k) a += pl[k] * hW1[k * DM + t];
    a = silu_f(a);
    float vv = a * hW2[t];
    int lane = t & 63, w = t >> 6;
    for (int off = 32; off > 0; off >>= 1) vv += __shfl_down(vv, off, 64);
    if (lane == 0) red[w] = vv;
    __syncthreads();
    if (t == 0) outp[g] = red[0] + red[1] + hb2[0];
}

// ---------------------------------------------------------------- per-layer folded constants
__global__ __launch_bounds__(256) void precompute_kernel(
    const float* __restrict__ msgW2, const float* __restrict__ msgb2,
    const float* __restrict__ updW1, const float* __restrict__ updb1,
    float* __restrict__ W2U, float* __restrict__ bias2)
{
    int bid = blockIdx.x; int t = threadIdx.x;
    if (bid < NL * DH) {
        int l = bid / DH, k = bid % DH;
        const float* w2row = msgW2 + (size_t)l * DH * DM + (size_t)k * DM;
        const float* u1 = updW1 + (size_t)l * 2 * DM * DH;
        float acc = 0.f;
        for (int j = 0; j < DM; ++j) acc += w2row[j] * u1[(size_t)(DM + j) * DH + t];
        W2U[(size_t)l * DH * DH + (size_t)k * DH + t] = acc;
    } else {
        int l = bid - NL * DH;
        const float* u1 = updW1 + (size_t)l * 2 * DM * DH;
        const float* b2 = msgb2 + (size_t)l * DM;
        float acc = updb1[(size_t)l * DH + t];
        for (int j = 0; j < DM; ++j) acc += 12.0f * b2[j] * u1[(size_t)(DM + j) * DH + t];
        bias2[(size_t)l * DH + t] = acc;
    }
}

// ---------------------------------------------------------------- weight transpose + bf16 split (coalesced)
struct WJob { const float* src; u16* dh; u16* dl; int K, N, ldd, off; };
struct WJobs { WJob j[16]; };
__global__ __launch_bounds__(256) void wprep_kernel(WJobs jobs) {
    WJob jb = jobs.j[blockIdx.y];
    int tiles_k = (jb.K + 31) / 32, tiles_n = (jb.N + 31) / 32;
    int tile = blockIdx.x;
    if (tile >= tiles_k * tiles_n) return;
    int kt = (tile % tiles_k) * 32, nt = (tile / tiles_k) * 32;
    __shared__ float tl[32][33];
    int i = threadIdx.x >> 5, j = threadIdx.x & 31;
    for (int r = i; r < 32; r += 8) {
        int k = kt + r, n = nt + j;
        if (k < jb.K && n < jb.N) tl[r][j] = jb.src[(size_t)k * jb.N + n];
    }
    __syncthreads();
    for (int r = i; r < 32; r += 8) {
        int n = nt + r, k = kt + j;
        if (n < jb.N && k < jb.K) {
            float v = tl[j][r];
            u16 hi = f2bf(v);
            u16 lo = f2bf(v - bf2f(hi));
            jb.dh[(size_t)n * jb.ldd + jb.off + k] = hi;
            jb.dl[(size_t)n * jb.ldd + jb.off + k] = lo;
        }
    }
}

extern "C" void kernel_launch(void* const* d_in, const int* in_sizes, int n_in,
                              void* d_out, int out_size, void* d_ws, size_t ws_size,
                              hipStream_t stream) {
    const float* x     = (const float*)d_in[0];
    const float* inW1  = (const float*)d_in[2];
    const float* inb1  = (const float*)d_in[3];
    const float* inW2  = (const float*)d_in[4];
    const float* inb2  = (const float*)d_in[5];
    const float* msgW1 = (const float*)d_in[6];
    const float* msgb1 = (const float*)d_in[7];
    const float* msgW2 = (const float*)d_in[8];
    const float* msgb2 = (const float*)d_in[9];
    const float* updW1 = (const float*)d_in[10];
    const float* updb1 = (const float*)d_in[11];
    const float* updW2 = (const float*)d_in[12];
    const float* updb2 = (const float*)d_in[13];
    const float* nw    = (const float*)d_in[14];
    const float* nb    = (const float*)d_in[15];
    const float* nms   = (const float*)d_in[16];
    const float* gW1   = (const float*)d_in[17];
    const float* gb1   = (const float*)d_in[18];
    const float* gW2   = (const float*)d_in[19];
    const float* gb2   = (const float*)d_in[20];
    const float* hW1   = (const float*)d_in[21];
    const float* hb1   = (const float*)d_in[22];
    const float* hW2   = (const float*)d_in[23];
    const float* hb2   = (const float*)d_in[24];
    float* outp = (float*)d_out;

    float* ws    = (float*)d_ws;
    float* h     = ws;                              // N*DM fp32
    float* CSb   = h + (size_t)NPTS * DM;           // N*512 fp32 [C|S]
    float* hnb   = CSb + (size_t)NPTS * 512;        // N*DM fp32
    float* W2U   = hnb + (size_t)NPTS * DM;         // 3*DH*DH
    float* bias2 = W2U + (size_t)NL * DH * DH;      // 3*DH
    float* glb   = bias2 + NL * DH;                 // N
    int*   srcb  = (int*)(glb + NPTS);              // E
    float* eab   = (float*)(srcb + EDG);            // E*4
    float* psum  = eab + (size_t)EDG * 4;           // 16*8*2*128
    float* gstat = psum + 16 * 8 * 2 * DM;          // 32
    float* ppool = gstat + 32;                      // 16*8*128
    u16* hh  = (u16*)(ppool + 16 * 8 * DM);         // N*DM
    u16* hl  = hh + (size_t)NPTS * DM;
    u16* HSh = hl + (size_t)NPTS * DM;              // N*DH
    u16* HSl = HSh + (size_t)NPTS * DH;
    u16* Th  = HSl + (size_t)NPTS * DH;             // N*DH
    u16* Tl  = Th + (size_t)NPTS * DH;
    u16* WCSh = Tl + (size_t)NPTS * DH;              u16* WCSl = WCSh + (size_t)NL * 512 * DM;
    u16* WTh = WCSl + (size_t)NL * 512 * DM;         u16* WTl = WTh + (size_t)NL * DH * 384;
    u16* WUh = WTl + (size_t)NL * DH * 384;          u16* WUl = WUh + (size_t)NL * DM * DH;
    u16* WGh = WUl + (size_t)NL * DM * DH;           u16* WGl = WGh + (size_t)DM * DM;

    hipLaunchKernelGGL(precompute_kernel, dim3(NL * DH + NL), dim3(DH), 0, stream,
                       msgW2, msgb2, updW1, updb1, W2U, bias2);

    WJobs jobs;
    int ji = 0;
    for (int l = 0; l < NL; ++l) {
        jobs.j[ji++] = WJob{ msgW1 + (size_t)l * 260 * DH,            WCSh + (size_t)l * 512 * DM,            WCSl + (size_t)l * 512 * DM,            128, 256, 128, 0 };
        jobs.j[ji++] = WJob{ msgW1 + (size_t)l * 260 * DH + 128 * DH, WCSh + (size_t)l * 512 * DM + 256 * DM, WCSl + (size_t)l * 512 * DM + 256 * DM, 128, 256, 128, 0 };
        jobs.j[ji++] = WJob{ updW1 + (size_t)l * 256 * DH,            WTh + (size_t)l * DH * 384, WTl + (size_t)l * DH * 384, 128, 256, 384, 0 };
        jobs.j[ji++] = WJob{ W2U   + (size_t)l * DH * DH,             WTh + (size_t)l * DH * 384, WTl + (size_t)l * DH * 384, 256, 256, 384, 128 };
        jobs.j[ji++] = WJob{ updW2 + (size_t)l * DH * DM,             WUh + (size_t)l * DM * DH, WUl + (size_t)l * DM * DH, 256, 128, 256, 0 };
    }
    jobs.j[ji++] = WJob{ gW1, WGh, WGl, 128, 128, 128, 0 };
    hipLaunchKernelGGL(wprep_kernel, dim3(64, 16), dim3(256), 0, stream, jobs);

    hipLaunchKernelGGL(knn_kernel, dim3(NPTS / KPPB), dim3(256), 0, stream, x, srcb, eab);
    hipLaunchKernelGGL(in_mlp_kernel, dim3(NPTS / 8), dim3(128), 0, stream,
                       x, inW1, inb1, inW2, inb2, h, hh, hl);

    for (int l = 0; l < NL; ++l) {
        const float* W1l = msgW1 + (size_t)l * 260 * DH;
        // [C|S] = h @ [W1top|W1mid] + [msg_b1|0]   (128x128 tiles, 512 blocks)
        hipLaunchKernelGGL(mgemm128_kernel, dim3(NPTS / M2BM, 512 / MBN), dim3(256), 0, stream,
            hh, hl, DM, DM, (const u16*)nullptr, (const u16*)nullptr, 0,
            WCSh + (size_t)l * 512 * DM, WCSl + (size_t)l * 512 * DM, DM,
            msgb1 + (size_t)l * DH, 256,
            CSb, (u16*)nullptr, (u16*)nullptr, 512, 0);
        // HS[i] = sum_e silu(C[i] + S[src] + ea.W1ea)  -> split bf16
        hipLaunchKernelGGL(edge_agg_kernel, dim3(NPTS / EPB), dim3(DH), 0, stream,
            CSb, srcb, eab, W1l + (size_t)2 * DM * DH, HSh, HSl);
        // T = silu([h|HS] @ WT + bias2) -> split bf16  (64x128 tiles, 512 blocks)
        hipLaunchKernelGGL(mgemm_kernel, dim3(NPTS / MBM, DH / MBN), dim3(256), 0, stream,
            hh, hl, DM, DM, HSh, HSl, DH,
            WTh + (size_t)l * DH * 384, WTl + (size_t)l * DH * 384, 384,
            bias2 + (size_t)l * DH, DH, (const float*)nullptr, 0,
            (float*)nullptr, Th, Tl, DH, 1);
        // hn = h + T @ U2 + upd_b2
        hipLaunchKernelGGL(mgemm_kernel, dim3(NPTS / MBM, DM / MBN), dim3(256), 0, stream,
            Th, Tl, DH, DH, (const u16*)nullptr, (const u16*)nullptr, 0,
            WUh + (size_t)l * DM * DH, WUl + (size_t)l * DM * DH, DH,
            updb2 + (size_t)l * DM, DM, h, DM,
            hnb, (u16*)nullptr, (u16*)nullptr, DM, 0);
        // h = graph_norm(hn), dual-write
        hipLaunchKernelGGL(norm_part_kernel, dim3(BGR, 8), dim3(256), 0, stream, hnb, psum);
        hipLaunchKernelGGL(norm_apply_kernel, dim3(BGR, 8), dim3(256), 0, stream,
            hnb, h, hh, hl, psum, nw + (size_t)l * DM, nb + (size_t)l * DM, nms + (size_t)l * DM);
    }

    // gl = tanh(h @ gW1 + gb1) . gW2 + gb2  (fused GEMM + dot)
    hipLaunchKernelGGL(gate_gemm_kernel, dim3(NPTS / 64), dim3(256), 0, stream,
        hh, hl, WGh, WGl, gb1, gW2, gb2, glb);

    hipLaunchKernelGGL(pool_stats_kernel, dim3(BGR), dim3(256), 0, stream, glb, gstat);
    hipLaunchKernelGGL(pool_part_kernel, dim3(BGR, 8), dim3(256), 0, stream, h, glb, gstat, ppool);
    hipLaunchKernelGGL(pool_head_kernel, dim3(BGR), dim3(128), 0, stream,
        ppool, gstat, hW1, hb1, hW2, hb2, outp);
}